// Round 8
// baseline (2945.132 us; speedup 1.0000x reference)
//
#include <hip/hip_runtime.h>
#include <math.h>

#define NSTACKC 4
#define FD 8
#define HD 64
#define KD 10
#define MD 29
#define TBF 4.0f
#define ROWS 64      // rows per block (= lanes per wave)
#define LDSP 9       // padded LDS row stride (gcd(9,32)=1 -> conflict-free)
#define H1CH 16      // h1 chunk size (h2[64] is the long-lived accumulator)
// LDS inflation: 2 buffers x 7168 floats = 57344 B/block. 160KB/CU / 56KB ->
// exactly 2 workgroups/CU = 16 waves/CU = 4 waves/SIMD. The GCN scheduler's
// occupancy target = min(LDS-limit, reg-limit); with LDS capping it at 4/EU,
// the register budget is 512/4 = 128 and the allocator has NO incentive to
// squeeze below ~124 (R1's proven spill-free allocation for this body).
// R2-R7 showed attributes CANNOT do this: min-waves only sets the reg CAP;
// the scheduler picked 8/EU (64 regs) on its own and spilled h2[64] ->
// 1.4-2.2 GB scratch traffic -> 42% VALUBusy.
#define LDSN 7168

__device__ __forceinline__ float splus(float v) {
    // softplus: log1p(exp(v)), stable for large v
    return (v > 20.0f) ? v : log1pf(__expf(v));
}

__global__ void nsf_wavefeat_kernel(
    const float* __restrict__ X,
    const float* __restrict__ W0,
    const float* __restrict__ B0,
    const float* __restrict__ W1,
    const float* __restrict__ B1,
    const float* __restrict__ W2,
    const float* __restrict__ B2,
    float* __restrict__ OUT,
    int Bn)
{
    __shared__ float xs[2][LDSN];

    const int t    = threadIdx.x;
    const int lane = t & 63;
    // wave id == feature index; force into SGPR so weight addrs are provably uniform
    const int wid  = __builtin_amdgcn_readfirstlane(t >> 6);
    const size_t rowbase = (size_t)blockIdx.x * ROWS;

    // cooperative slab load: thread t loads element t of the block's 512-float slab
    {
        int r = t >> 3, f = t & 7;
        float v = 0.0f;
        if (rowbase + r < (size_t)Bn) v = X[rowbase * FD + t];
        xs[0][r * LDSP + f] = v;
    }
    __syncthreads();

    #pragma unroll
    for (int s = 0; s < NSTACKC; ++s) {
        const int rb = s & 1;        // read buffer
        const int wb = rb ^ 1;       // write buffer (disjoint -> no read/write aliasing)

        // ---- read this stack's x (reversal of prev stack's y baked into slot) ----
        float x[FD];
        #pragma unroll
        for (int f = 0; f < FD; ++f) {
            int slot = (s == 0) ? f : (FD - 1 - f);
            x[f] = xs[rb][lane * LDSP + slot];
        }
        float xi = 0.0f;
        #pragma unroll
        for (int f = 0; f < FD; ++f) if (wid == f) xi = x[f];  // scalar selects

        const float* w0s = W0 + (((size_t)s * FD + wid) * FD) * HD;
        const float* b0s = B0 + ((size_t)s * FD + wid) * HD;
        const float* w1s = W1 + (((size_t)s * FD + wid) * HD) * HD;
        const float* b1s = B1 + ((size_t)s * FD + wid) * HD;
        const float* w2s = W2 + (((size_t)s * FD + wid) * HD) * MD;
        const float* b2s = B2 + ((size_t)s * FD + wid) * MD;

        // ---- layers 1+2 fused: h2[64] accumulates; h1 computed in chunks of 16 ----
        float h2[HD];
        #pragma unroll
        for (int oo = 0; oo < HD; ++oo) h2[oo] = b1s[oo];

        #pragma unroll
        for (int c = 0; c < HD / H1CH; ++c) {
            float h1c[H1CH];
            #pragma unroll
            for (int j = 0; j < H1CH; ++j) h1c[j] = b0s[c * H1CH + j];
            #pragma unroll
            for (int f = 0; f < FD; ++f) {
                if (f <= wid) {  // wave-uniform branch, skips whole FMA block
                    float xf = x[f];
                    const float* wrow = w0s + f * HD + c * H1CH;
                    #pragma unroll
                    for (int j = 0; j < H1CH; ++j)
                        h1c[j] = fmaf(xf, wrow[j], h1c[j]);
                }
            }
            #pragma unroll
            for (int j = 0; j < H1CH; ++j) {
                float hv = fmaxf(h1c[j], 0.0f);
                const float* wrow = w1s + (c * H1CH + j) * HD;
                #pragma unroll
                for (int oo = 0; oo < HD; ++oo)
                    h2[oo] = fmaf(hv, wrow[oo], h2[oo]);
            }
        }

        // ---- layer 3: 64 -> 29 (h2 dead after this; p becomes live) ----
        float p[MD];
        #pragma unroll
        for (int m = 0; m < MD; ++m) p[m] = b2s[m];
        #pragma unroll
        for (int hh = 0; hh < HD; ++hh) {
            float hv = fmaxf(h2[hh], 0.0f);
            const float* wrow = w2s + hh * MD;
            #pragma unroll
            for (int m = 0; m < MD; ++m)
                p[m] = fmaf(hv, wrow[m], p[m]);
        }

        // ---- rational-quadratic spline on feature wid ----
        // widths
        float mw = p[0];
        #pragma unroll
        for (int k = 1; k < KD; ++k) mw = fmaxf(mw, p[k]);
        float ew[KD];
        float sw = 0.0f;
        #pragma unroll
        for (int k = 0; k < KD; ++k) { ew[k] = __expf(p[k] - mw); sw += ew[k]; }
        float invw = 1.0f / sw;
        float cw[KD + 1];
        cw[0] = -TBF;
        {
            float acc = 0.0f;
            #pragma unroll
            for (int k = 0; k < KD; ++k) {
                float wk = 0.001f + (1.0f - 0.001f * KD) * ew[k] * invw;
                acc += wk;
                cw[k + 1] = 2.0f * TBF * acc - TBF;
            }
        }
        cw[KD] = TBF;

        // heights
        float mh = p[KD];
        #pragma unroll
        for (int k = 1; k < KD; ++k) mh = fmaxf(mh, p[KD + k]);
        float eh[KD];
        float sh = 0.0f;
        #pragma unroll
        for (int k = 0; k < KD; ++k) { eh[k] = __expf(p[KD + k] - mh); sh += eh[k]; }
        float invh = 1.0f / sh;
        float ch[KD + 1];
        ch[0] = -TBF;
        {
            float acc = 0.0f;
            #pragma unroll
            for (int k = 0; k < KD; ++k) {
                float hk = 0.001f + (1.0f - 0.001f * KD) * eh[k] * invh;
                acc += hk;
                ch[k + 1] = 2.0f * TBF * acc - TBF;
            }
        }
        ch[KD] = TBF;

        // derivatives: d[0]=d[10]=MIN_D+softplus(const)==1.0 exactly
        float d[KD + 1];
        d[0] = 1.0f;
        d[KD] = 1.0f;
        #pragma unroll
        for (int k = 1; k < KD; ++k) d[k] = 0.001f + splus(p[2 * KD + (k - 1)]);

        float xc = fminf(fmaxf(xi, -TBF), TBF);

        // bin select: monotone cndmask chain
        float w_b  = cw[1] - cw[0];
        float cw_b = cw[0];
        float h_b  = ch[1] - ch[0];
        float ch_b = ch[0];
        float d_b  = d[0];
        float d_p1 = d[1];
        #pragma unroll
        for (int k = 1; k < KD; ++k) {
            bool c = xc >= cw[k];
            w_b  = c ? (cw[k + 1] - cw[k]) : w_b;
            cw_b = c ? cw[k] : cw_b;
            h_b  = c ? (ch[k + 1] - ch[k]) : h_b;
            ch_b = c ? ch[k] : ch_b;
            d_b  = c ? d[k] : d_b;
            d_p1 = c ? d[k + 1] : d_p1;
        }

        float theta = (xc - cw_b) / w_b;
        float t1m   = theta * (1.0f - theta);
        float delta = h_b / w_b;
        float num   = h_b * (delta * theta * theta + d_b * t1m);
        float den   = delta + (d_b + d_p1 - 2.0f * delta) * t1m;
        float yv    = ch_b + num / den;
        bool inside = (xi >= -TBF) && (xi <= TBF);
        float y = inside ? yv : xi;

        // ---- write y to its feature slot in the WRITE buffer (disjoint from reads) ----
        xs[wb][lane * LDSP + wid] = y;
        __syncthreads();   // one barrier per stack: orders this write vs next read
    } // s

    // coalesced store of final slab (NSTACKC even -> final data is in xs[0])
    {
        int r = t >> 3, f = t & 7;
        if (rowbase + r < (size_t)Bn)
            OUT[rowbase * FD + t] = xs[0][r * LDSP + f];
    }
}

extern "C" void kernel_launch(void* const* d_in, const int* in_sizes, int n_in,
                              void* d_out, int out_size, void* d_ws, size_t ws_size,
                              hipStream_t stream) {
    const float* X  = (const float*)d_in[0];
    const float* W0 = (const float*)d_in[1];
    const float* B0 = (const float*)d_in[2];
    const float* W1 = (const float*)d_in[3];
    const float* B1 = (const float*)d_in[4];
    const float* W2 = (const float*)d_in[5];
    const float* B2 = (const float*)d_in[6];
    float* OUT = (float*)d_out;

    int Bn = in_sizes[0] / FD;
    int blocks = (Bn + ROWS - 1) / ROWS;
    hipLaunchKernelGGL(nsf_wavefeat_kernel, dim3(blocks), dim3(512), 0, stream,
                       X, W0, B0, W1, B1, W2, B2, OUT, Bn);
}